// Round 9
// baseline (50.026 us; speedup 1.0000x reference)
//
#include <hip/hip_runtime.h>

// YOLO loss: out,label [32768,17,7,7] f32 -> scalar f32.
// One BATCH per WAVE, lane = cell (lanes 49..63 clamp, contribution zeroed).
// 34 constant-offset coalesced dword loads per batch; mask = channel-0 label
// register itself (exactly 0/1):
//   contrib = d0^2*(0.5+0.5m) + m*(5*(loc+siz)+cls)
//   siz via (sqrt l - sqrt o)^2 = l+o-2*sqrt(l*o)   (one v_sqrt_f32)
// Tail: ONE plain device-scope atomicAdd per block into d_out (pre-zeroed by
// a 4-byte hipMemsetAsync). NO __threadfence -- R4/R7 showed a per-block
// device fence costs 3x (L2 cache maintenance serializes streaming traffic);
// the atomic alone is coherent on gfx950 and needs none. Ordering varies
// only final ulps (threshold 3.3e-2).
// Sum / (32768*49).

#define CELLS  49
#define BPC    833            // 17*49
#define NBATCH 32768
#define NBLK   2048           // 8192 waves -> 4 batches per wave

__global__ __launch_bounds__(256) void yolo_loss(const float* __restrict__ outp,
                                                 const float* __restrict__ lab,
                                                 float* __restrict__ res) {
    const int lane   = threadIdx.x & 63;
    const int wid    = threadIdx.x >> 6;
    const int gwave  = (blockIdx.x * 256 + threadIdx.x) >> 6;   // global wave id
    const int nwaves = (NBLK * 256) >> 6;                       // 8192
    const int cell   = (lane < CELLS) ? lane : (CELLS - 1);     // clamp lanes 49..63
    const bool valid = (lane < CELLS);

    float acc = 0.0f;
    for (int b = gwave; b < NBATCH; b += nwaves) {
        const float* __restrict__ lb = lab  + b * BPC + cell;
        const float* __restrict__ ob = outp + b * BPC + cell;

        float l[17], o[17];
#pragma unroll
        for (int c = 0; c < 17; ++c) {      // constant offsets -> offset: imm
            l[c] = lb[c * CELLS];
            o[c] = ob[c * CELLS];
        }

        const float m  = l[0];              // objectness label == mask (0 or 1)
        const float d0 = m - o[0];

        float loc = 0.0f, cls = 0.0f, siz = 0.0f;
#pragma unroll
        for (int c = 1; c <= 2; ++c) { const float d = l[c] - o[c]; loc = fmaf(d, d, loc); }
#pragma unroll
        for (int c = 3; c <= 4; ++c) {      // (sqrt l - sqrt o)^2 = l+o-2*sqrt(l*o)
            const float t = l[c] + o[c];
            const float s = __builtin_amdgcn_sqrtf(l[c] * o[c]);
            siz += fmaf(-2.0f, s, t);
        }
#pragma unroll
        for (int c = 5; c < 17; ++c) { const float d = l[c] - o[c]; cls = fmaf(d, d, cls); }

        const float contrib = d0 * d0 * fmaf(0.5f, m, 0.5f)
                            + m * fmaf(5.0f, loc + siz, cls);
        acc += valid ? contrib : 0.0f;
    }

    // wave64 shuffle reduce
#pragma unroll
    for (int off = 32; off > 0; off >>= 1)
        acc += __shfl_down(acc, off, 64);

    __shared__ float wsum[4];
    if (lane == 0) wsum[wid] = acc;
    __syncthreads();
    if (threadIdx.x == 0)
        atomicAdd(res, (wsum[0] + wsum[1] + wsum[2] + wsum[3]) * (1.0f / 1605632.0f));
}

extern "C" void kernel_launch(void* const* d_in, const int* in_sizes, int n_in,
                              void* d_out, int out_size, void* d_ws, size_t ws_size,
                              hipStream_t stream) {
    const float* outp = (const float*)d_in[0];
    const float* lab  = (const float*)d_in[1];
    float* res        = (float*)d_out;

    hipMemsetAsync(res, 0, sizeof(float), stream);     // graph-capturable
    yolo_loss<<<NBLK, 256, 0, stream>>>(outp, lab, res);
}

// Round 10
// 48.534 us; speedup vs baseline: 1.0307x; 1.0307x over previous
//
#include <hip/hip_runtime.h>

// YOLO loss: out,label [32768,17,7,7] f32 -> scalar f32.
// One BATCH per WAVE, lane = cell (lanes 49..63 clamp, contribution zeroed).
// 34 constant-offset coalesced dword loads per batch; mask = channel-0 label
// register itself (exactly 0/1):
//   contrib = d0^2*(0.5+0.5m) + m*(5*(loc+siz)+cls)
//   siz via (sqrt l - sqrt o)^2 = l+o-2*sqrt(l*o)   (one v_sqrt_f32)
// Tail: ONE plain device-scope atomicAdd per block into d_out. No
// __threadfence (R4/R7: per-block device fence = 3x slowdown from L2 cache
// maintenance). d_out zeroed by a 1-wave COMPUTE kernel -- NOT hipMemsetAsync:
// R9 showed a 4-byte SDMA memset inside a captured graph costs ~11 us of
// compute<->SDMA engine sync. Sum / (32768*49).

#define CELLS  49
#define BPC    833            // 17*49
#define NBATCH 32768
#define NBLK   2048           // 8192 waves -> 4 batches per wave

__global__ void yolo_zero(float* __restrict__ res) {
    if (threadIdx.x == 0) res[0] = 0.0f;
}

__global__ __launch_bounds__(256) void yolo_loss(const float* __restrict__ outp,
                                                 const float* __restrict__ lab,
                                                 float* __restrict__ res) {
    const int lane   = threadIdx.x & 63;
    const int wid    = threadIdx.x >> 6;
    const int gwave  = (blockIdx.x * 256 + threadIdx.x) >> 6;   // global wave id
    const int nwaves = (NBLK * 256) >> 6;                       // 8192
    const int cell   = (lane < CELLS) ? lane : (CELLS - 1);     // clamp lanes 49..63
    const bool valid = (lane < CELLS);

    float acc = 0.0f;
    for (int b = gwave; b < NBATCH; b += nwaves) {
        const float* __restrict__ lb = lab  + b * BPC + cell;
        const float* __restrict__ ob = outp + b * BPC + cell;

        float l[17], o[17];
#pragma unroll
        for (int c = 0; c < 17; ++c) {      // constant offsets -> offset: imm
            l[c] = lb[c * CELLS];
            o[c] = ob[c * CELLS];
        }

        const float m  = l[0];              // objectness label == mask (0 or 1)
        const float d0 = m - o[0];

        float loc = 0.0f, cls = 0.0f, siz = 0.0f;
#pragma unroll
        for (int c = 1; c <= 2; ++c) { const float d = l[c] - o[c]; loc = fmaf(d, d, loc); }
#pragma unroll
        for (int c = 3; c <= 4; ++c) {      // (sqrt l - sqrt o)^2 = l+o-2*sqrt(l*o)
            const float t = l[c] + o[c];
            const float s = __builtin_amdgcn_sqrtf(l[c] * o[c]);
            siz += fmaf(-2.0f, s, t);
        }
#pragma unroll
        for (int c = 5; c < 17; ++c) { const float d = l[c] - o[c]; cls = fmaf(d, d, cls); }

        const float contrib = d0 * d0 * fmaf(0.5f, m, 0.5f)
                            + m * fmaf(5.0f, loc + siz, cls);
        acc += valid ? contrib : 0.0f;
    }

    // wave64 shuffle reduce
#pragma unroll
    for (int off = 32; off > 0; off >>= 1)
        acc += __shfl_down(acc, off, 64);

    __shared__ float wsum[4];
    if (lane == 0) wsum[wid] = acc;
    __syncthreads();
    if (threadIdx.x == 0)
        atomicAdd(res, (wsum[0] + wsum[1] + wsum[2] + wsum[3]) * (1.0f / 1605632.0f));
}

extern "C" void kernel_launch(void* const* d_in, const int* in_sizes, int n_in,
                              void* d_out, int out_size, void* d_ws, size_t ws_size,
                              hipStream_t stream) {
    const float* outp = (const float*)d_in[0];
    const float* lab  = (const float*)d_in[1];
    float* res        = (float*)d_out;

    yolo_zero<<<1, 64, 0, stream>>>(res);              // compute-engine zero
    yolo_loss<<<NBLK, 256, 0, stream>>>(outp, lab, res);
}

// Round 11
// 41.097 us; speedup vs baseline: 1.2173x; 1.1810x over previous
//
#include <hip/hip_runtime.h>

// YOLO loss: out,label [32768,17,7,7] f32 -> scalar f32.
// FINAL STRUCTURE (best measured: 38.4 us R5, 38.7 us R8).
// One BATCH per WAVE, lane = cell (lanes 49..63 clamp, contribution zeroed).
// 34 constant-offset coalesced dword loads per batch; a wave's loads cover
// two contiguous 3332 B regions -> zero overfetch (FETCH ~= ideal/2, L3
// serves the rest). Mask = channel-0 label register itself (exactly 0/1):
//   contrib = d0^2*(0.5+0.5m) + m*(5*(loc+siz)+cls)
//   siz via (sqrt l - sqrt o)^2 = l+o-2*sqrt(l*o)   (one v_sqrt_f32)
// Sum / (32768*49). Two-kernel deterministic reduction.
//
// Tail-structure findings on gfx950 (do not "optimize" these back in):
//  - __threadfence() last-block tail: +70 us (R4/R7) — per-block device fence
//    issues L2 cache maintenance that serializes all streaming traffic.
//  - f32 atomicAdd of 2048 block sums to one address: +10 us (R9/R10),
//    regardless of whether d_out is zeroed by SDMA memset or a zero-kernel.
//  - A separate 1-block reduce kernel costs only ~4-5 us incl. graph gap.

#define CELLS  49
#define BPC    833            // 17*49
#define NBATCH 32768
#define NBLK   2048           // 8192 waves -> 4 batches per wave

__global__ __launch_bounds__(256) void yolo_partial(const float* __restrict__ outp,
                                                    const float* __restrict__ lab,
                                                    float* __restrict__ partial) {
    const int lane   = threadIdx.x & 63;
    const int gwave  = (blockIdx.x * 256 + threadIdx.x) >> 6;   // global wave id
    const int nwaves = (NBLK * 256) >> 6;                       // 8192
    const int cell   = (lane < CELLS) ? lane : (CELLS - 1);     // clamp lanes 49..63
    const bool valid = (lane < CELLS);

    float acc = 0.0f;
    for (int b = gwave; b < NBATCH; b += nwaves) {
        const float* __restrict__ lb = lab  + b * BPC + cell;
        const float* __restrict__ ob = outp + b * BPC + cell;

        float l[17], o[17];
#pragma unroll
        for (int c = 0; c < 17; ++c) {      // constant offsets -> offset: imm
            l[c] = lb[c * CELLS];
            o[c] = ob[c * CELLS];
        }

        const float m  = l[0];              // objectness label == mask (0 or 1)
        const float d0 = m - o[0];

        float loc = 0.0f, cls = 0.0f, siz = 0.0f;
#pragma unroll
        for (int c = 1; c <= 2; ++c) { const float d = l[c] - o[c]; loc = fmaf(d, d, loc); }
#pragma unroll
        for (int c = 3; c <= 4; ++c) {      // (sqrt l - sqrt o)^2 = l+o-2*sqrt(l*o)
            const float t = l[c] + o[c];
            const float s = __builtin_amdgcn_sqrtf(l[c] * o[c]);
            siz += fmaf(-2.0f, s, t);
        }
#pragma unroll
        for (int c = 5; c < 17; ++c) { const float d = l[c] - o[c]; cls = fmaf(d, d, cls); }

        const float contrib = d0 * d0 * fmaf(0.5f, m, 0.5f)
                            + m * fmaf(5.0f, loc + siz, cls);
        acc += valid ? contrib : 0.0f;
    }

    // wave64 shuffle reduce
#pragma unroll
    for (int off = 32; off > 0; off >>= 1)
        acc += __shfl_down(acc, off, 64);

    __shared__ float wsum[4];
    const int wid = threadIdx.x >> 6;
    if (lane == 0) wsum[wid] = acc;
    __syncthreads();
    if (threadIdx.x == 0)
        partial[blockIdx.x] = wsum[0] + wsum[1] + wsum[2] + wsum[3];
}

__global__ __launch_bounds__(256) void yolo_final(const float* __restrict__ partial,
                                                  float* __restrict__ outv) {
    float acc = 0.0f;
    for (int i = threadIdx.x; i < NBLK; i += 256) acc += partial[i];
#pragma unroll
    for (int off = 32; off > 0; off >>= 1)
        acc += __shfl_down(acc, off, 64);

    __shared__ float wsum[4];
    const int lane = threadIdx.x & 63;
    const int wid  = threadIdx.x >> 6;
    if (lane == 0) wsum[wid] = acc;
    __syncthreads();
    if (threadIdx.x == 0)
        outv[0] = (wsum[0] + wsum[1] + wsum[2] + wsum[3]) * (1.0f / 1605632.0f);
}

extern "C" void kernel_launch(void* const* d_in, const int* in_sizes, int n_in,
                              void* d_out, int out_size, void* d_ws, size_t ws_size,
                              hipStream_t stream) {
    const float* outp = (const float*)d_in[0];
    const float* lab  = (const float*)d_in[1];
    float* partial    = (float*)d_ws;          // NBLK floats (8 KB)
    float* res        = (float*)d_out;

    yolo_partial<<<NBLK, 256, 0, stream>>>(outp, lab, partial);
    yolo_final<<<1, 256, 0, stream>>>(partial, res);
}